// Round 12
// baseline (1155.352 us; speedup 1.0000x reference)
//
#include <hip/hip_runtime.h>
#include <hip/hip_bf16.h>

typedef __bf16    bf16x8_t __attribute__((ext_vector_type(8)));
typedef float     f32x4_t  __attribute__((ext_vector_type(4)));
typedef short     s16x4_t  __attribute__((ext_vector_type(4)));
typedef short     s16x8_t  __attribute__((ext_vector_type(8)));
typedef unsigned  u32x4_t  __attribute__((ext_vector_type(4)));

#define S_LEN 2048
#define HDIM  64
#define BQ    32
#define NTHREADS 512
#define PSTR_B 4112
#define BMSTR 264

__device__ __forceinline__ short f2bf(float f) {
    return __builtin_bit_cast(short, (__bf16)f);
}
__device__ __forceinline__ float bf2f(short s) {
    return __builtin_bit_cast(float, ((unsigned)(unsigned short)s) << 16);
}
__device__ __forceinline__ short* pelem(short* P, int row, int e) {
    return (short*)((char*)P + (unsigned)row * PSTR_B + (unsigned)e * 2u);
}
__device__ __forceinline__ const short* pelemc(const short* P, int row, int e) {
    return pelem(const_cast<short*>(P), row, e);
}
__device__ __forceinline__ unsigned nzmask16(u32x4_t w) {
    unsigned n = 0;
    #pragma unroll
    for (int i = 0; i < 4; ++i) {
        const unsigned x = w[i];
        const unsigned t = (x & 0x7F7F7F7Fu) + 0x7F7F7F7Fu;
        const unsigned z = ((t | x) & 0x80808080u) >> 7;
        n |= ((z * 0x10204081u) >> 28) << (4 * i);
    }
    return n;
}
__device__ __forceinline__ unsigned nzmask4w(u32x4_t w) {
    return (w[0] ? 1u : 0u) | (w[1] ? 2u : 0u) | (w[2] ? 4u : 0u) | (w[3] ? 8u : 0u);
}

#define PK8(lo, hi, out8) { s16x8_t _t; \
    _t[0]=f2bf((lo)[0]); _t[1]=f2bf((lo)[1]); _t[2]=f2bf((lo)[2]); _t[3]=f2bf((lo)[3]); \
    _t[4]=f2bf((hi)[0]); _t[5]=f2bf((hi)[1]); _t[6]=f2bf((hi)[2]); _t[7]=f2bf((hi)[3]); \
    (out8) = __builtin_bit_cast(bf16x8_t, _t); }
#define PKV(src, dst) { s16x8_t _t; \
    _t[0]=f2bf((src)[0]); _t[1]=f2bf((src)[1]); _t[2]=f2bf((src)[2]); _t[3]=f2bf((src)[3]); \
    _t[4]=f2bf((src)[4]); _t[5]=f2bf((src)[5]); _t[6]=f2bf((src)[6]); _t[7]=f2bf((src)[7]); \
    (dst) = __builtin_bit_cast(bf16x8_t, _t); }

__global__ void detect_mask(const unsigned char* __restrict__ M, int* __restrict__ flags) {
    __shared__ int cnt[4];
    if (threadIdx.x < 4) cnt[threadIdx.x] = 0;
    __syncthreads();
    int local[4] = {0, 0, 0, 0};
    for (int i = threadIdx.x; i < 16384; i += 256)
        if (M[i]) local[i & 3]++;
    #pragma unroll
    for (int c = 0; c < 4; ++c)
        if (local[c]) atomicAdd(&cnt[c], local[c]);
    __syncthreads();
    if (threadIdx.x == 0) {
        int stride;
        if (cnt[1] == 0 && cnt[2] == 0 && cnt[3] == 0)      stride = 4;  // int32
        else if (cnt[0] == 0 && cnt[1] == 0)                stride = 4;  // float32
        else                                                stride = 1;  // bool/int8
        flags[0] = stride;
    }
}

// PROBE P1 (grid 4096 = 2x work -> slowest kernel, readable in top-5; /2 for
// true phase-1 time): mask bitmask + QK^T + exp + P->LDS + rowsum ONLY.
// P kept live via post-barrier read; garbage ctx overwritten by final kernel.
__global__ __launch_bounds__(NTHREADS, 2)
void probe_p1(const float* __restrict__ Q, const float* __restrict__ K,
              const unsigned char* __restrict__ M, const int* __restrict__ MF,
              float* __restrict__ OUT)
{
    __shared__ short Plds[BQ * (PSTR_B / 2)];
    __shared__ unsigned char Bm[BQ * BMSTR];
    __shared__ float rowsum[BQ];
    __shared__ float rinv_s[BQ];

    const int tid  = threadIdx.x;
    const int w    = tid >> 6;
    const int lane = tid & 63;
    const int col  = lane & 15;
    const int kg   = lane >> 4;
    const int mstride = MF[0];

    const int id2  = blockIdx.x & 2047;      // two blocks per tile, same work
    const int slot = id2 >> 3;
    const int b    = ((slot >> 6) << 3) | (id2 & 7);
    const int q0   = (slot & 63) * BQ;

    if (tid < BQ) rowsum[tid] = 0.f;

    {   // mask tile -> bitmask (identical to main)
        const int row  = tid >> 4;
        const int segE = (tid & 15) * 128;
        unsigned long long bits[2] = {0ull, 0ull};
        if (mstride == 1) {
            const unsigned char* mp = M + (size_t)b * S_LEN * S_LEN
                                        + (size_t)(q0 + row) * S_LEN + segE;
            #pragma unroll
            for (int j = 0; j < 8; ++j)
                bits[j >> 2] |= (unsigned long long)nzmask16(*(const u32x4_t*)(mp + j * 16))
                                << (16 * (j & 3));
        } else {
            const unsigned* mp = (const unsigned*)M + (size_t)b * S_LEN * S_LEN
                                   + (size_t)(q0 + row) * S_LEN + segE;
            #pragma unroll
            for (int j = 0; j < 32; ++j)
                bits[j >> 4] |= (unsigned long long)nzmask4w(*(const u32x4_t*)(mp + j * 4))
                                << (4 * (j & 15));
        }
        unsigned long long* bp = (unsigned long long*)&Bm[row * BMSTR + (tid & 15) * 16];
        bp[0] = bits[0]; bp[1] = bits[1];
    }

    bf16x8_t af[2][2];
    #pragma unroll
    for (int m = 0; m < 2; ++m)
        #pragma unroll
        for (int kk = 0; kk < 2; ++kk) {
            const float* qp = Q + ((size_t)b * S_LEN + q0 + m * 16 + col) * HDIM + kk * 32 + kg * 8;
            const f32x4_t qa = *(const f32x4_t*)qp;
            const f32x4_t qb = *(const f32x4_t*)(qp + 4);
            PK8(qa, qb, af[m][kk]);
        }
    __syncthreads();

    float rs[2][4] = {{0.f,0.f,0.f,0.f},{0.f,0.f,0.f,0.f}};
    {
        const float* Kb = K + (size_t)b * S_LEN * HDIM;
        f32x4_t A0,B0,C0,D0, A1,B1,C1,D1;
#define LDK(f, AX,BX,CX,DX) { \
    const float* kp = Kb + (size_t)(w * 256 + (f) * 16 + col) * HDIM + kg * 8; \
    AX = *(const f32x4_t*)kp;        BX = *(const f32x4_t*)(kp + 4); \
    CX = *(const f32x4_t*)(kp + 32); DX = *(const f32x4_t*)(kp + 36); }
#define STEP(f, AX,BX,CX,DX, PF, fp) { \
    bf16x8_t kb0, kb1; PK8(AX, BX, kb0); PK8(CX, DX, kb1); \
    if (PF) LDK(fp, AX,BX,CX,DX); \
    f32x4_t acc0 = {0.f,0.f,0.f,0.f}, acc1 = {0.f,0.f,0.f,0.f}; \
    acc0 = __builtin_amdgcn_mfma_f32_16x16x32_bf16(af[0][0], kb0, acc0, 0,0,0); \
    acc0 = __builtin_amdgcn_mfma_f32_16x16x32_bf16(af[0][1], kb1, acc0, 0,0,0); \
    acc1 = __builtin_amdgcn_mfma_f32_16x16x32_bf16(af[1][0], kb0, acc1, 0,0,0); \
    acc1 = __builtin_amdgcn_mfma_f32_16x16x32_bf16(af[1][1], kb1, acc1, 0,0,0); \
    const int c = w * 256 + (f) * 16 + col; \
    _Pragma("unroll") \
    for (int r = 0; r < 4; ++r) { \
        const int row0 = kg * 4 + r; \
        const unsigned b0m = Bm[row0 * BMSTR + (c >> 3)]; \
        const float p0 = ((b0m >> (c & 7)) & 1u) ? 0.f : __expf(acc0[r] * 0.125f); \
        rs[0][r] += p0; \
        *pelem(Plds, row0, c) = f2bf(p0); \
        const int row1 = 16 + kg * 4 + r; \
        const unsigned b1m = Bm[row1 * BMSTR + (c >> 3)]; \
        const float p1 = ((b1m >> (c & 7)) & 1u) ? 0.f : __expf(acc1[r] * 0.125f); \
        rs[1][r] += p1; \
        *pelem(Plds, row1, c) = f2bf(p1); \
    } }
        LDK(0, A0,B0,C0,D0);
        LDK(1, A1,B1,C1,D1);
        #pragma unroll
        for (int ff = 0; ff < 16; ff += 2) {
            STEP(ff,     A0,B0,C0,D0, (ff + 2 < 16), ff + 2);
            STEP(ff + 1, A1,B1,C1,D1, (ff + 3 < 16), ff + 3);
        }
#undef LDK
#undef STEP
    }
    #pragma unroll
    for (int m = 0; m < 2; ++m)
        #pragma unroll
        for (int r = 0; r < 4; ++r) {
            float s = rs[m][r];
            s += __shfl_xor(s, 1); s += __shfl_xor(s, 2);
            s += __shfl_xor(s, 4); s += __shfl_xor(s, 8);
            if (col == 0) atomicAdd(&rowsum[m * 16 + kg * 4 + r], s);
        }
    __syncthreads();
    if (tid < BQ) rinv_s[tid] = 1.0f / rowsum[tid];
    __syncthreads();

    // keep P live (post-barrier read) + garbage ctx write (overwritten later)
    if (w < 4) {
        const int hb = (w & 3) * 16;
        #pragma unroll
        for (int r = 0; r < 4; ++r) {
            const int row = kg * 4 + r;
            const float g = bf2f(*pelemc(Plds, row, hb + col)) * 1e-30f;
            OUT[((size_t)b * S_LEN + q0 + row) * HDIM + hb + col] = rinv_s[row] + g;
        }
    }
}

// PROBE P2 (grid 2048): phase 2 exactly — PV (V loads + P b128 LDS reads +
// MFMA) + attn store stream + ctx reduce/store. P prefilled (constant bf16).
__global__ __launch_bounds__(NTHREADS, 2)
void probe_p2(const float* __restrict__ V, const int* __restrict__ MF,
              float* __restrict__ OUT)
{
    __shared__ short Plds[BQ * (PSTR_B / 2)];
    __shared__ float Pvp[4][BQ][17];
    __shared__ float rinv_s[BQ];

    const int tid  = threadIdx.x;
    const int w    = tid >> 6;
    const int lane = tid & 63;
    const int col  = lane & 15;
    const int kg   = lane >> 4;

    const int id   = blockIdx.x;
    const int slot = id >> 3;
    const int b    = ((slot >> 6) << 3) | (id & 7);
    const int q0   = (slot & 63) * BQ;

    float* attn_out = OUT + (size_t)32 * S_LEN * HDIM;

    for (int i = tid; i < BQ * (PSTR_B / 2); i += NTHREADS) Plds[i] = (short)0x3F80;
    if (tid < BQ) rinv_s[tid] = 1.0f / 2048.0f;
    __syncthreads();

    const int hb    = (w & 3) * 16;
    const int kbase = (w >> 2) * 1024;
    const float* Vb = V + (size_t)b * S_LEN * HDIM;

    f32x4_t cacc0 = {0.f,0.f,0.f,0.f}, cacc1 = {0.f,0.f,0.f,0.f};
    {
        float vr0[8], vr1[8], vr2[8], vr3[8];
#define LOADV(kc, dst) { \
    const float* vp = Vb + (size_t)(kbase + (kc) * 32 + kg * 8) * HDIM + hb + col; \
    dst[0] = vp[0];        dst[1] = vp[HDIM];     dst[2] = vp[2*HDIM]; dst[3] = vp[3*HDIM]; \
    dst[4] = vp[4*HDIM];   dst[5] = vp[5*HDIM];   dst[6] = vp[6*HDIM]; dst[7] = vp[7*HDIM]; }
#define PVSTEP(kc, vsrc) { \
    bf16x8_t vbf; PKV(vsrc, vbf); \
    const int ke = kbase + (kc) * 32 + kg * 8; \
    const bf16x8_t pa0 = *(const bf16x8_t*)pelemc(Plds, col,      ke); \
    const bf16x8_t pa1 = *(const bf16x8_t*)pelemc(Plds, 16 + col, ke); \
    cacc0 = __builtin_amdgcn_mfma_f32_16x16x32_bf16(pa0, vbf, cacc0, 0,0,0); \
    cacc1 = __builtin_amdgcn_mfma_f32_16x16x32_bf16(pa1, vbf, cacc1, 0,0,0); }
        LOADV(0, vr0); LOADV(1, vr1); LOADV(2, vr2); LOADV(3, vr3);
        #pragma unroll
        for (int g = 0; g < 8; ++g) {
            PVSTEP(4 * g,     vr0); if (4 * g + 4 < 32) LOADV(4 * g + 4, vr0);
            PVSTEP(4 * g + 1, vr1); if (4 * g + 5 < 32) LOADV(4 * g + 5, vr1);
            PVSTEP(4 * g + 2, vr2); if (4 * g + 6 < 32) LOADV(4 * g + 6, vr2);
            PVSTEP(4 * g + 3, vr3); if (4 * g + 7 < 32) LOADV(4 * g + 7, vr3);
        }
#undef LOADV
#undef PVSTEP
    }

    {   // attn store stream (identical shape to main)
        const int srow = w * 4 + kg;
        const float my_rinv = rinv_s[srow];
        float* abp = attn_out + ((size_t)b * S_LEN + q0 + srow) * S_LEN + col * 4;
        #pragma unroll 4
        for (int sec = 0; sec < 32; ++sec) {
            const s16x4_t pv = *(const s16x4_t*)pelemc(Plds, srow, sec * 64 + col * 4);
            f32x4_t o;
            o[0] = bf2f(pv[0]) * my_rinv; o[1] = bf2f(pv[1]) * my_rinv;
            o[2] = bf2f(pv[2]) * my_rinv; o[3] = bf2f(pv[3]) * my_rinv;
            *(f32x4_t*)(abp + sec * 64) = o;
        }
    }

    if (w >= 4) {
        #pragma unroll
        for (int r = 0; r < 4; ++r) {
            Pvp[w - 4][kg * 4 + r][col]      = cacc0[r];
            Pvp[w - 4][16 + kg * 4 + r][col] = cacc1[r];
        }
    }
    __syncthreads();
    if (w < 4) {
        #pragma unroll
        for (int r = 0; r < 4; ++r) {
            const int row0 = kg * 4 + r;
            const int row1 = 16 + kg * 4 + r;
            OUT[((size_t)b * S_LEN + q0 + row0) * HDIM + hb + col]
                = (cacc0[r] + Pvp[w][row0][col]) * rinv_s[row0];
            OUT[((size_t)b * S_LEN + q0 + row1) * HDIM + hb + col]
                = (cacc1[r] + Pvp[w][row1][col]) * rinv_s[row1];
        }
    }
}

// FINAL kernel: r10 verbatim (correct output).
__global__ __launch_bounds__(NTHREADS, 2)
void sdpa_one(const float* __restrict__ Q, const float* __restrict__ K,
              const float* __restrict__ V, const unsigned char* __restrict__ M,
              const int* __restrict__ MF, float* __restrict__ OUT)
{
    __shared__ short Plds[BQ * (PSTR_B / 2)];
    __shared__ unsigned char Bm[BQ * BMSTR];
    __shared__ float Pvp[4][BQ][17];
    __shared__ float rowsum[BQ];
    __shared__ float rinv_s[BQ];

    const int tid  = threadIdx.x;
    const int w    = tid >> 6;
    const int lane = tid & 63;
    const int col  = lane & 15;
    const int kg   = lane >> 4;
    const int mstride = MF[0];

    const int id   = blockIdx.x;
    const int slot = id >> 3;
    const int b    = ((slot >> 6) << 3) | (id & 7);
    const int q0   = (slot & 63) * BQ;

    float* attn_out = OUT + (size_t)32 * S_LEN * HDIM;

    if (tid < BQ) rowsum[tid] = 0.f;

    {   // mask tile -> bitmask
        const int row  = tid >> 4;
        const int segE = (tid & 15) * 128;
        unsigned long long bits[2] = {0ull, 0ull};
        if (mstride == 1) {
            const unsigned char* mp = M + (size_t)b * S_LEN * S_LEN
                                        + (size_t)(q0 + row) * S_LEN + segE;
            #pragma unroll
            for (int j = 0; j < 8; ++j)
                bits[j >> 2] |= (unsigned long long)nzmask16(*(const u32x4_t*)(mp + j * 16))
                                << (16 * (j & 3));
        } else {
            const unsigned* mp = (const unsigned*)M + (size_t)b * S_LEN * S_LEN
                                   + (size_t)(q0 + row) * S_LEN + segE;
            #pragma unroll
            for (int j = 0; j < 32; ++j)
                bits[j >> 4] |= (unsigned long long)nzmask4w(*(const u32x4_t*)(mp + j * 4))
                                << (4 * (j & 15));
        }
        unsigned long long* bp = (unsigned long long*)&Bm[row * BMSTR + (tid & 15) * 16];
        bp[0] = bits[0]; bp[1] = bits[1];
    }

    bf16x8_t af[2][2];
    #pragma unroll
    for (int m = 0; m < 2; ++m)
        #pragma unroll
        for (int kk = 0; kk < 2; ++kk) {
            const float* qp = Q + ((size_t)b * S_LEN + q0 + m * 16 + col) * HDIM + kk * 32 + kg * 8;
            const f32x4_t qa = *(const f32x4_t*)qp;
            const f32x4_t qb = *(const f32x4_t*)(qp + 4);
            PK8(qa, qb, af[m][kk]);
        }
    __syncthreads();

    float rs[2][4] = {{0.f,0.f,0.f,0.f},{0.f,0.f,0.f,0.f}};
    {
        const float* Kb = K + (size_t)b * S_LEN * HDIM;
        f32x4_t A0,B0,C0,D0, A1,B1,C1,D1;
#define LDK(f, AX,BX,CX,DX) { \
    const float* kp = Kb + (size_t)(w * 256 + (f) * 16 + col) * HDIM + kg * 8; \
    AX = *(const f32x4_t*)kp;        BX = *(const f32x4_t*)(kp + 4); \
    CX = *(const f32x4_t*)(kp + 32); DX = *(const f32x4_t*)(kp + 36); }
#define STEP(f, AX,BX,CX,DX, PF, fp) { \
    bf16x8_t kb0, kb1; PK8(AX, BX, kb0); PK8(CX, DX, kb1); \
    if (PF) LDK(fp, AX,BX,CX,DX); \
    f32x4_t acc0 = {0.f,0.f,0.f,0.f}, acc1 = {0.f,0.f,0.f,0.f}; \
    acc0 = __builtin_amdgcn_mfma_f32_16x16x32_bf16(af[0][0], kb0, acc0, 0,0,0); \
    acc0 = __builtin_amdgcn_mfma_f32_16x16x32_bf16(af[0][1], kb1, acc0, 0,0,0); \
    acc1 = __builtin_amdgcn_mfma_f32_16x16x32_bf16(af[1][0], kb0, acc1, 0,0,0); \
    acc1 = __builtin_amdgcn_mfma_f32_16x16x32_bf16(af[1][1], kb1, acc1, 0,0,0); \
    const int c = w * 256 + (f) * 16 + col; \
    _Pragma("unroll") \
    for (int r = 0; r < 4; ++r) { \
        const int row0 = kg * 4 + r; \
        const unsigned b0m = Bm[row0 * BMSTR + (c >> 3)]; \
        const float p0 = ((b0m >> (c & 7)) & 1u) ? 0.f : __expf(acc0[r] * 0.125f); \
        rs[0][r] += p0; \
        *pelem(Plds, row0, c) = f2bf(p0); \
        const int row1 = 16 + kg * 4 + r; \
        const unsigned b1m = Bm[row1 * BMSTR + (c >> 3)]; \
        const float p1 = ((b1m >> (c & 7)) & 1u) ? 0.f : __expf(acc1[r] * 0.125f); \
        rs[1][r] += p1; \
        *pelem(Plds, row1, c) = f2bf(p1); \
    } }
        LDK(0, A0,B0,C0,D0);
        LDK(1, A1,B1,C1,D1);
        #pragma unroll
        for (int ff = 0; ff < 16; ff += 2) {
            STEP(ff,     A0,B0,C0,D0, (ff + 2 < 16), ff + 2);
            STEP(ff + 1, A1,B1,C1,D1, (ff + 3 < 16), ff + 3);
        }
#undef LDK
#undef STEP
    }
    #pragma unroll
    for (int m = 0; m < 2; ++m)
        #pragma unroll
        for (int r = 0; r < 4; ++r) {
            float s = rs[m][r];
            s += __shfl_xor(s, 1); s += __shfl_xor(s, 2);
            s += __shfl_xor(s, 4); s += __shfl_xor(s, 8);
            if (col == 0) atomicAdd(&rowsum[m * 16 + kg * 4 + r], s);
        }
    __syncthreads();
    if (tid < BQ) rinv_s[tid] = 1.0f / rowsum[tid];
    __syncthreads();

    const int hb    = (w & 3) * 16;
    const int kbase = (w >> 2) * 1024;
    const float* Vb = V + (size_t)b * S_LEN * HDIM;

    f32x4_t cacc0 = {0.f,0.f,0.f,0.f}, cacc1 = {0.f,0.f,0.f,0.f};
    {
        float vr0[8], vr1[8], vr2[8], vr3[8];
#define LOADV(kc, dst) { \
    const float* vp = Vb + (size_t)(kbase + (kc) * 32 + kg * 8) * HDIM + hb + col; \
    dst[0] = vp[0];        dst[1] = vp[HDIM];     dst[2] = vp[2*HDIM]; dst[3] = vp[3*HDIM]; \
    dst[4] = vp[4*HDIM];   dst[5] = vp[5*HDIM];   dst[6] = vp[6*HDIM]; dst[7] = vp[7*HDIM]; }
#define PVSTEP(kc, vsrc) { \
    bf16x8_t vbf; PKV(vsrc, vbf); \
    const int ke = kbase + (kc) * 32 + kg * 8; \
    const bf16x8_t pa0 = *(const bf16x8_t*)pelemc(Plds, col,      ke); \
    const bf16x8_t pa1 = *(const bf16x8_t*)pelemc(Plds, 16 + col, ke); \
    cacc0 = __builtin_amdgcn_mfma_f32_16x16x32_bf16(pa0, vbf, cacc0, 0,0,0); \
    cacc1 = __builtin_amdgcn_mfma_f32_16x16x32_bf16(pa1, vbf, cacc1, 0,0,0); }
        LOADV(0, vr0); LOADV(1, vr1); LOADV(2, vr2); LOADV(3, vr3);
        #pragma unroll
        for (int g = 0; g < 8; ++g) {
            PVSTEP(4 * g,     vr0); if (4 * g + 4 < 32) LOADV(4 * g + 4, vr0);
            PVSTEP(4 * g + 1, vr1); if (4 * g + 5 < 32) LOADV(4 * g + 5, vr1);
            PVSTEP(4 * g + 2, vr2); if (4 * g + 6 < 32) LOADV(4 * g + 6, vr2);
            PVSTEP(4 * g + 3, vr3); if (4 * g + 7 < 32) LOADV(4 * g + 7, vr3);
        }
#undef LOADV
#undef PVSTEP
    }

    {
        const int srow = w * 4 + kg;
        const float my_rinv = rinv_s[srow];
        float* abp = attn_out + ((size_t)b * S_LEN + q0 + srow) * S_LEN + col * 4;
        #pragma unroll 4
        for (int sec = 0; sec < 32; ++sec) {
            const s16x4_t pv = *(const s16x4_t*)pelemc(Plds, srow, sec * 64 + col * 4);
            f32x4_t o;
            o[0] = bf2f(pv[0]) * my_rinv; o[1] = bf2f(pv[1]) * my_rinv;
            o[2] = bf2f(pv[2]) * my_rinv; o[3] = bf2f(pv[3]) * my_rinv;
            *(f32x4_t*)(abp + sec * 64) = o;
        }
    }

    if (w >= 4) {
        #pragma unroll
        for (int r = 0; r < 4; ++r) {
            Pvp[w - 4][kg * 4 + r][col]      = cacc0[r];
            Pvp[w - 4][16 + kg * 4 + r][col] = cacc1[r];
        }
    }
    __syncthreads();
    if (w < 4) {
        #pragma unroll
        for (int r = 0; r < 4; ++r) {
            const int row0 = kg * 4 + r;
            const int row1 = 16 + kg * 4 + r;
            OUT[((size_t)b * S_LEN + q0 + row0) * HDIM + hb + col]
                = (cacc0[r] + Pvp[w][row0][col]) * rinv_s[row0];
            OUT[((size_t)b * S_LEN + q0 + row1) * HDIM + hb + col]
                = (cacc1[r] + Pvp[w][row1][col]) * rinv_s[row1];
        }
    }
}

extern "C" void kernel_launch(void* const* d_in, const int* in_sizes, int n_in,
                              void* d_out, int out_size, void* d_ws, size_t ws_size,
                              hipStream_t stream)
{
    const float* q = (const float*)d_in[0];
    const float* k = (const float*)d_in[1];
    const float* v = (const float*)d_in[2];
    const unsigned char* mask = (const unsigned char*)d_in[3];
    int* mflags = (int*)d_ws;
    float* out = (float*)d_out;
    detect_mask<<<dim3(1), dim3(256), 0, stream>>>(mask, mflags);
    // diagnostics (all outputs overwritten by the final full kernel)
    probe_p1<<<dim3(4096), dim3(NTHREADS), 0, stream>>>(q, k, mask, mflags, out);
    probe_p2<<<dim3(2048), dim3(NTHREADS), 0, stream>>>(v, mflags, out);
    // real kernel, unchanged from r10
    sdpa_one<<<dim3(2048), dim3(NTHREADS), 0, stream>>>(q, k, v, mask, mflags, out);
}

// Round 13
// 431.570 us; speedup vs baseline: 2.6771x; 2.6771x over previous
//
#include <hip/hip_runtime.h>
#include <hip/hip_bf16.h>

typedef __bf16    bf16x8_t __attribute__((ext_vector_type(8)));
typedef float     f32x4_t  __attribute__((ext_vector_type(4)));
typedef short     s16x4_t  __attribute__((ext_vector_type(4)));
typedef short     s16x8_t  __attribute__((ext_vector_type(8)));
typedef unsigned  u32x4_t  __attribute__((ext_vector_type(4)));

#define S_LEN 2048
#define HDIM  64
#define BQ    32
#define NTHREADS 512
#define PSTR_B 4112       // P row byte stride; %128B=16 -> rows shift 4 banks
#define BMSTR 264

__device__ __forceinline__ short f2bf(float f) {
    return __builtin_bit_cast(short, (__bf16)f);
}
__device__ __forceinline__ float bf2f(short s) {
    return __builtin_bit_cast(float, ((unsigned)(unsigned short)s) << 16);
}
__device__ __forceinline__ short* pelem(short* P, int row, int e) {
    return (short*)((char*)P + (unsigned)row * PSTR_B + (unsigned)e * 2u);
}
__device__ __forceinline__ const short* pelemc(const short* P, int row, int e) {
    return pelem(const_cast<short*>(P), row, e);
}
__device__ __forceinline__ unsigned nzmask16(u32x4_t w) {
    unsigned n = 0;
    #pragma unroll
    for (int i = 0; i < 4; ++i) {
        const unsigned x = w[i];
        const unsigned t = (x & 0x7F7F7F7Fu) + 0x7F7F7F7Fu;
        const unsigned z = ((t | x) & 0x80808080u) >> 7;
        n |= ((z * 0x10204081u) >> 28) << (4 * i);
    }
    return n;
}
__device__ __forceinline__ unsigned nzmask4w(u32x4_t w) {
    return (w[0] ? 1u : 0u) | (w[1] ? 2u : 0u) | (w[2] ? 4u : 0u) | (w[3] ? 8u : 0u);
}

#define PK8(lo, hi, out8) { s16x8_t _t; \
    _t[0]=f2bf((lo)[0]); _t[1]=f2bf((lo)[1]); _t[2]=f2bf((lo)[2]); _t[3]=f2bf((lo)[3]); \
    _t[4]=f2bf((hi)[0]); _t[5]=f2bf((hi)[1]); _t[6]=f2bf((hi)[2]); _t[7]=f2bf((hi)[3]); \
    (out8) = __builtin_bit_cast(bf16x8_t, _t); }
#define PKV(src, dst) { s16x8_t _t; \
    _t[0]=f2bf((src)[0]); _t[1]=f2bf((src)[1]); _t[2]=f2bf((src)[2]); _t[3]=f2bf((src)[3]); \
    _t[4]=f2bf((src)[4]); _t[5]=f2bf((src)[5]); _t[6]=f2bf((src)[6]); _t[7]=f2bf((src)[7]); \
    (dst) = __builtin_bit_cast(bf16x8_t, _t); }

__global__ void detect_mask(const unsigned char* __restrict__ M, int* __restrict__ flags) {
    __shared__ int cnt[4];
    if (threadIdx.x < 4) cnt[threadIdx.x] = 0;
    __syncthreads();
    int local[4] = {0, 0, 0, 0};
    for (int i = threadIdx.x; i < 16384; i += 256)
        if (M[i]) local[i & 3]++;
    #pragma unroll
    for (int c = 0; c < 4; ++c)
        if (local[c]) atomicAdd(&cnt[c], local[c]);
    __syncthreads();
    if (threadIdx.x == 0) {
        int stride;
        if (cnt[1] == 0 && cnt[2] == 0 && cnt[3] == 0)      stride = 4;  // int32
        else if (cnt[0] == 0 && cnt[1] == 0)                stride = 4;  // float32
        else                                                stride = 1;  // bool/int8
        flags[0] = stride;
    }
}

// r10 + (a) swapped QK^T MFMA operands (lane owns 4 consecutive k of ONE
// q-row -> 1 ds_write_b64 per acc, scalar rowsum) and (b) K prefetch depth 4,
// V prefetch depth 8 (dependency distance > HBM-miss latency).
__global__ __launch_bounds__(NTHREADS, 2)
void sdpa_one(const float* __restrict__ Q, const float* __restrict__ K,
              const float* __restrict__ V, const unsigned char* __restrict__ M,
              const int* __restrict__ MF, float* __restrict__ OUT)
{
    __shared__ short Plds[BQ * (PSTR_B / 2)];      // 131584 B unnormalized exp bf16
    __shared__ unsigned char Bm[BQ * BMSTR];       // 8448 B mask bits
    __shared__ float Pvp[4][BQ][17];               // PV k-half partials
    __shared__ float rowsum[BQ];
    __shared__ float rinv_s[BQ];

    const int tid  = threadIdx.x;
    const int w    = tid >> 6;
    const int lane = tid & 63;
    const int col  = lane & 15;
    const int kg   = lane >> 4;
    const int mstride = MF[0];

    // 2048 blocks = 8 xcd * 256 slots (bijective)
    const int id   = blockIdx.x;
    const int slot = id >> 3;
    const int b    = ((slot >> 6) << 3) | (id & 7);
    const int q0   = (slot & 63) * BQ;

    float* attn_out = OUT + (size_t)32 * S_LEN * HDIM;

    if (tid < BQ) rowsum[tid] = 0.f;

    {   // ---- mask tile -> 1-bit/elem LDS bitmask
        const int row  = tid >> 4;
        const int segE = (tid & 15) * 128;
        unsigned long long bits[2] = {0ull, 0ull};
        if (mstride == 1) {
            const unsigned char* mp = M + (size_t)b * S_LEN * S_LEN
                                        + (size_t)(q0 + row) * S_LEN + segE;
            #pragma unroll
            for (int j = 0; j < 8; ++j)
                bits[j >> 2] |= (unsigned long long)nzmask16(*(const u32x4_t*)(mp + j * 16))
                                << (16 * (j & 3));
        } else {
            const unsigned* mp = (const unsigned*)M + (size_t)b * S_LEN * S_LEN
                                   + (size_t)(q0 + row) * S_LEN + segE;
            #pragma unroll
            for (int j = 0; j < 32; ++j)
                bits[j >> 4] |= (unsigned long long)nzmask4w(*(const u32x4_t*)(mp + j * 4))
                                << (4 * (j & 15));
        }
        unsigned long long* bp = (unsigned long long*)&Bm[row * BMSTR + (tid & 15) * 16];
        bp[0] = bits[0]; bp[1] = bits[1];
    }

    // Q fragments (serve as MFMA *B* operand after the swap; same lane layout)
    bf16x8_t af[2][2];
    #pragma unroll
    for (int m = 0; m < 2; ++m)
        #pragma unroll
        for (int kk = 0; kk < 2; ++kk) {
            const float* qp = Q + ((size_t)b * S_LEN + q0 + m * 16 + col) * HDIM + kk * 32 + kg * 8;
            const f32x4_t qa = *(const f32x4_t*)qp;
            const f32x4_t qb = *(const f32x4_t*)(qp + 4);
            PK8(qa, qb, af[m][kk]);
        }
    __syncthreads();

    // ---- Phase 1: P^T-free swapped QK^T. D = mfma(A=K_frag, B=Q_frag):
    // lane(col,kg) reg r -> P[q=m*16+col][k = n0 + kg*4 + r] (4 consecutive k).
    float rs0 = 0.f, rs1 = 0.f;     // per-lane partial rowsum of q-row col / 16+col
    {
        const float* Kb = K + (size_t)b * S_LEN * HDIM;
        f32x4_t A0,B0,C0,D0, A1,B1,C1,D1, A2,B2,C2,D2, A3,B3,C3,D3;
#define LDK(f, AX,BX,CX,DX) { \
    const float* kp = Kb + (size_t)(w * 256 + (f) * 16 + col) * HDIM + kg * 8; \
    AX = *(const f32x4_t*)kp;        BX = *(const f32x4_t*)(kp + 4); \
    CX = *(const f32x4_t*)(kp + 32); DX = *(const f32x4_t*)(kp + 36); }
#define STEP(f, AX,BX,CX,DX, PF, fp) { \
    bf16x8_t kb0, kb1; PK8(AX, BX, kb0); PK8(CX, DX, kb1); \
    if (PF) LDK(fp, AX,BX,CX,DX); \
    f32x4_t acc0 = {0.f,0.f,0.f,0.f}, acc1 = {0.f,0.f,0.f,0.f}; \
    acc0 = __builtin_amdgcn_mfma_f32_16x16x32_bf16(kb0, af[0][0], acc0, 0,0,0); \
    acc0 = __builtin_amdgcn_mfma_f32_16x16x32_bf16(kb1, af[0][1], acc0, 0,0,0); \
    acc1 = __builtin_amdgcn_mfma_f32_16x16x32_bf16(kb0, af[1][0], acc1, 0,0,0); \
    acc1 = __builtin_amdgcn_mfma_f32_16x16x32_bf16(kb1, af[1][1], acc1, 0,0,0); \
    const int c0 = w * 256 + (f) * 16 + kg * 4; \
    const int sh = c0 & 7;            /* 0 or 4 */ \
    { const unsigned bb = Bm[col * BMSTR + (c0 >> 3)]; \
      float p0 = ((bb >> (sh    )) & 1u) ? 0.f : __expf(acc0[0] * 0.125f); \
      float p1 = ((bb >> (sh + 1)) & 1u) ? 0.f : __expf(acc0[1] * 0.125f); \
      float p2 = ((bb >> (sh + 2)) & 1u) ? 0.f : __expf(acc0[2] * 0.125f); \
      float p3 = ((bb >> (sh + 3)) & 1u) ? 0.f : __expf(acc0[3] * 0.125f); \
      rs0 += (p0 + p1) + (p2 + p3); \
      s16x4_t pk; pk[0]=f2bf(p0); pk[1]=f2bf(p1); pk[2]=f2bf(p2); pk[3]=f2bf(p3); \
      *(s16x4_t*)pelem(Plds, col, c0) = pk; } \
    { const unsigned bb = Bm[(16 + col) * BMSTR + (c0 >> 3)]; \
      float p0 = ((bb >> (sh    )) & 1u) ? 0.f : __expf(acc1[0] * 0.125f); \
      float p1 = ((bb >> (sh + 1)) & 1u) ? 0.f : __expf(acc1[1] * 0.125f); \
      float p2 = ((bb >> (sh + 2)) & 1u) ? 0.f : __expf(acc1[2] * 0.125f); \
      float p3 = ((bb >> (sh + 3)) & 1u) ? 0.f : __expf(acc1[3] * 0.125f); \
      rs1 += (p0 + p1) + (p2 + p3); \
      s16x4_t pk; pk[0]=f2bf(p0); pk[1]=f2bf(p1); pk[2]=f2bf(p2); pk[3]=f2bf(p3); \
      *(s16x4_t*)pelem(Plds, 16 + col, c0) = pk; } }
        LDK(0, A0,B0,C0,D0);
        LDK(1, A1,B1,C1,D1);
        LDK(2, A2,B2,C2,D2);
        LDK(3, A3,B3,C3,D3);
        #pragma unroll
        for (int ff = 0; ff < 16; ff += 4) {
            STEP(ff,     A0,B0,C0,D0, (ff + 4 < 16), ff + 4);
            STEP(ff + 1, A1,B1,C1,D1, (ff + 5 < 16), ff + 5);
            STEP(ff + 2, A2,B2,C2,D2, (ff + 6 < 16), ff + 6);
            STEP(ff + 3, A3,B3,C3,D3, (ff + 7 < 16), ff + 7);
        }
#undef LDK
#undef STEP
    }
    // rowsum: combine kg groups (lane, lane^16, lane^32, lane^48), one atomic
    {
        float s0 = rs0, s1 = rs1;
        s0 += __shfl_xor(s0, 16); s0 += __shfl_xor(s0, 32);
        s1 += __shfl_xor(s1, 16); s1 += __shfl_xor(s1, 32);
        if (lane < 16) {
            atomicAdd(&rowsum[col], s0);
            atomicAdd(&rowsum[16 + col], s1);
        }
    }
    __syncthreads();
    if (tid < BQ) rinv_s[tid] = 1.0f / rowsum[tid];
    __syncthreads();

    // ---- Phase 2a: pure PV, V prefetch depth 8
    const int hb    = (w & 3) * 16;
    const int kbase = (w >> 2) * 1024;
    const float* Vb = V + (size_t)b * S_LEN * HDIM;

    f32x4_t cacc0 = {0.f,0.f,0.f,0.f}, cacc1 = {0.f,0.f,0.f,0.f};
    {
        float vr0[8], vr1[8], vr2[8], vr3[8], vr4[8], vr5[8], vr6[8], vr7[8];
#define LOADV(kc, dst) { \
    const float* vp = Vb + (size_t)(kbase + (kc) * 32 + kg * 8) * HDIM + hb + col; \
    dst[0] = vp[0];        dst[1] = vp[HDIM];     dst[2] = vp[2*HDIM]; dst[3] = vp[3*HDIM]; \
    dst[4] = vp[4*HDIM];   dst[5] = vp[5*HDIM];   dst[6] = vp[6*HDIM]; dst[7] = vp[7*HDIM]; }
#define PVSTEP(kc, vsrc) { \
    bf16x8_t vbf; PKV(vsrc, vbf); \
    const int ke = kbase + (kc) * 32 + kg * 8; \
    const bf16x8_t pa0 = *(const bf16x8_t*)pelemc(Plds, col,      ke); \
    const bf16x8_t pa1 = *(const bf16x8_t*)pelemc(Plds, 16 + col, ke); \
    cacc0 = __builtin_amdgcn_mfma_f32_16x16x32_bf16(pa0, vbf, cacc0, 0,0,0); \
    cacc1 = __builtin_amdgcn_mfma_f32_16x16x32_bf16(pa1, vbf, cacc1, 0,0,0); }
        LOADV(0, vr0); LOADV(1, vr1); LOADV(2, vr2); LOADV(3, vr3);
        LOADV(4, vr4); LOADV(5, vr5); LOADV(6, vr6); LOADV(7, vr7);
        #pragma unroll
        for (int gg = 0; gg < 4; ++gg) {
            PVSTEP(8*gg,     vr0); if (8*gg +  8 < 32) LOADV(8*gg +  8, vr0);
            PVSTEP(8*gg + 1, vr1); if (8*gg +  9 < 32) LOADV(8*gg +  9, vr1);
            PVSTEP(8*gg + 2, vr2); if (8*gg + 10 < 32) LOADV(8*gg + 10, vr2);
            PVSTEP(8*gg + 3, vr3); if (8*gg + 11 < 32) LOADV(8*gg + 11, vr3);
            PVSTEP(8*gg + 4, vr4); if (8*gg + 12 < 32) LOADV(8*gg + 12, vr4);
            PVSTEP(8*gg + 5, vr5); if (8*gg + 13 < 32) LOADV(8*gg + 13, vr5);
            PVSTEP(8*gg + 6, vr6); if (8*gg + 14 < 32) LOADV(8*gg + 14, vr6);
            PVSTEP(8*gg + 7, vr7); if (8*gg + 15 < 32) LOADV(8*gg + 15, vr7);
        }
#undef LOADV
#undef PVSTEP
    }

    // ---- Phase 2b: attn store stream (proven ~free when overlapped)
    {
        const int srow = w * 4 + kg;
        const float my_rinv = rinv_s[srow];
        float* abp = attn_out + ((size_t)b * S_LEN + q0 + srow) * S_LEN + col * 4;
        #pragma unroll 4
        for (int sec = 0; sec < 32; ++sec) {
            const s16x4_t pv = *(const s16x4_t*)pelemc(Plds, srow, sec * 64 + col * 4);
            f32x4_t o;
            o[0] = bf2f(pv[0]) * my_rinv; o[1] = bf2f(pv[1]) * my_rinv;
            o[2] = bf2f(pv[2]) * my_rinv; o[3] = bf2f(pv[3]) * my_rinv;
            *(f32x4_t*)(abp + sec * 64) = o;
        }
    }

    // ---- ctx: reduce k-halves, normalize, store
    if (w >= 4) {
        #pragma unroll
        for (int r = 0; r < 4; ++r) {
            Pvp[w - 4][kg * 4 + r][col]      = cacc0[r];
            Pvp[w - 4][16 + kg * 4 + r][col] = cacc1[r];
        }
    }
    __syncthreads();
    if (w < 4) {
        #pragma unroll
        for (int r = 0; r < 4; ++r) {
            const int row0 = kg * 4 + r;
            const int row1 = 16 + kg * 4 + r;
            OUT[((size_t)b * S_LEN + q0 + row0) * HDIM + hb + col]
                = (cacc0[r] + Pvp[w][row0][col]) * rinv_s[row0];
            OUT[((size_t)b * S_LEN + q0 + row1) * HDIM + hb + col]
                = (cacc1[r] + Pvp[w][row1][col]) * rinv_s[row1];
        }
    }
}

extern "C" void kernel_launch(void* const* d_in, const int* in_sizes, int n_in,
                              void* d_out, int out_size, void* d_ws, size_t ws_size,
                              hipStream_t stream)
{
    const float* q = (const float*)d_in[0];
    const float* k = (const float*)d_in[1];
    const float* v = (const float*)d_in[2];
    const unsigned char* mask = (const unsigned char*)d_in[3];
    int* mflags = (int*)d_ws;
    float* out = (float*)d_out;
    detect_mask<<<dim3(1), dim3(256), 0, stream>>>(mask, mflags);
    sdpa_one<<<dim3(2048), dim3(NTHREADS), 0, stream>>>(q, k, v, mask, mflags, out);
}

// Round 14
// 431.178 us; speedup vs baseline: 2.6795x; 1.0009x over previous
//
#include <hip/hip_runtime.h>
#include <hip/hip_bf16.h>

typedef __bf16    bf16x8_t __attribute__((ext_vector_type(8)));
typedef float     f32x4_t  __attribute__((ext_vector_type(4)));
typedef short     s16x4_t  __attribute__((ext_vector_type(4)));
typedef short     s16x8_t  __attribute__((ext_vector_type(8)));
typedef unsigned  u32x4_t  __attribute__((ext_vector_type(4)));

#define S_LEN 2048
#define HDIM  64
#define BQ    32
#define NTHREADS 512
#define PSTR_B 4112       // P row byte stride; %128B=16 -> rows shift 4 banks
#define BMSTR 264

__device__ __forceinline__ short f2bf(float f) {
    return __builtin_bit_cast(short, (__bf16)f);
}
__device__ __forceinline__ float bf2f(short s) {
    return __builtin_bit_cast(float, ((unsigned)(unsigned short)s) << 16);
}
__device__ __forceinline__ short* pelem(short* P, int row, int e) {
    return (short*)((char*)P + (unsigned)row * PSTR_B + (unsigned)e * 2u);
}
__device__ __forceinline__ const short* pelemc(const short* P, int row, int e) {
    return pelem(const_cast<short*>(P), row, e);
}
__device__ __forceinline__ unsigned nzmask16(u32x4_t w) {
    unsigned n = 0;
    #pragma unroll
    for (int i = 0; i < 4; ++i) {
        const unsigned x = w[i];
        const unsigned t = (x & 0x7F7F7F7Fu) + 0x7F7F7F7Fu;
        const unsigned z = ((t | x) & 0x80808080u) >> 7;
        n |= ((z * 0x10204081u) >> 28) << (4 * i);
    }
    return n;
}
__device__ __forceinline__ unsigned nzmask4w(u32x4_t w) {
    return (w[0] ? 1u : 0u) | (w[1] ? 2u : 0u) | (w[2] ? 4u : 0u) | (w[3] ? 8u : 0u);
}

#define PK8(lo, hi, out8) { s16x8_t _t; \
    _t[0]=f2bf((lo)[0]); _t[1]=f2bf((lo)[1]); _t[2]=f2bf((lo)[2]); _t[3]=f2bf((lo)[3]); \
    _t[4]=f2bf((hi)[0]); _t[5]=f2bf((hi)[1]); _t[6]=f2bf((hi)[2]); _t[7]=f2bf((hi)[3]); \
    (out8) = __builtin_bit_cast(bf16x8_t, _t); }
#define PKV(src, dst) { s16x8_t _t; \
    _t[0]=f2bf((src)[0]); _t[1]=f2bf((src)[1]); _t[2]=f2bf((src)[2]); _t[3]=f2bf((src)[3]); \
    _t[4]=f2bf((src)[4]); _t[5]=f2bf((src)[5]); _t[6]=f2bf((src)[6]); _t[7]=f2bf((src)[7]); \
    (dst) = __builtin_bit_cast(bf16x8_t, _t); }

__global__ void detect_mask(const unsigned char* __restrict__ M, int* __restrict__ flags) {
    __shared__ int cnt[4];
    if (threadIdx.x < 4) cnt[threadIdx.x] = 0;
    __syncthreads();
    int local[4] = {0, 0, 0, 0};
    for (int i = threadIdx.x; i < 16384; i += 256)
        if (M[i]) local[i & 3]++;
    #pragma unroll
    for (int c = 0; c < 4; ++c)
        if (local[c]) atomicAdd(&cnt[c], local[c]);
    __syncthreads();
    if (threadIdx.x == 0) {
        int stride;
        if (cnt[1] == 0 && cnt[2] == 0 && cnt[3] == 0)      stride = 4;  // int32
        else if (cnt[0] == 0 && cnt[1] == 0)                stride = 4;  // float32
        else                                                stride = 1;  // bool/int8
        flags[0] = stride;
    }
}

// r10 + (a) swapped QK^T MFMA operands (lane owns 4 consecutive k of ONE
// q-row -> 1 ds_write_b64 per acc, scalar rowsum) and (b) K prefetch depth 4,
// V prefetch depth 8 (dependency distance > HBM-miss latency).
__global__ __launch_bounds__(NTHREADS, 2)
void sdpa_one(const float* __restrict__ Q, const float* __restrict__ K,
              const float* __restrict__ V, const unsigned char* __restrict__ M,
              const int* __restrict__ MF, float* __restrict__ OUT)
{
    __shared__ short Plds[BQ * (PSTR_B / 2)];      // 131584 B unnormalized exp bf16
    __shared__ unsigned char Bm[BQ * BMSTR];       // 8448 B mask bits
    __shared__ float Pvp[4][BQ][17];               // PV k-half partials
    __shared__ float rowsum[BQ];
    __shared__ float rinv_s[BQ];

    const int tid  = threadIdx.x;
    const int w    = tid >> 6;
    const int lane = tid & 63;
    const int col  = lane & 15;
    const int kg   = lane >> 4;
    const int mstride = MF[0];

    // 2048 blocks = 8 xcd * 256 slots (bijective)
    const int id   = blockIdx.x;
    const int slot = id >> 3;
    const int b    = ((slot >> 6) << 3) | (id & 7);
    const int q0   = (slot & 63) * BQ;

    float* attn_out = OUT + (size_t)32 * S_LEN * HDIM;

    if (tid < BQ) rowsum[tid] = 0.f;

    {   // ---- mask tile -> 1-bit/elem LDS bitmask
        const int row  = tid >> 4;
        const int segE = (tid & 15) * 128;
        unsigned long long bits[2] = {0ull, 0ull};
        if (mstride == 1) {
            const unsigned char* mp = M + (size_t)b * S_LEN * S_LEN
                                        + (size_t)(q0 + row) * S_LEN + segE;
            #pragma unroll
            for (int j = 0; j < 8; ++j)
                bits[j >> 2] |= (unsigned long long)nzmask16(*(const u32x4_t*)(mp + j * 16))
                                << (16 * (j & 3));
        } else {
            const unsigned* mp = (const unsigned*)M + (size_t)b * S_LEN * S_LEN
                                   + (size_t)(q0 + row) * S_LEN + segE;
            #pragma unroll
            for (int j = 0; j < 32; ++j)
                bits[j >> 4] |= (unsigned long long)nzmask4w(*(const u32x4_t*)(mp + j * 4))
                                << (4 * (j & 15));
        }
        unsigned long long* bp = (unsigned long long*)&Bm[row * BMSTR + (tid & 15) * 16];
        bp[0] = bits[0]; bp[1] = bits[1];
    }

    // Q fragments (serve as MFMA *B* operand after the swap; same lane layout)
    bf16x8_t af[2][2];
    #pragma unroll
    for (int m = 0; m < 2; ++m)
        #pragma unroll
        for (int kk = 0; kk < 2; ++kk) {
            const float* qp = Q + ((size_t)b * S_LEN + q0 + m * 16 + col) * HDIM + kk * 32 + kg * 8;
            const f32x4_t qa = *(const f32x4_t*)qp;
            const f32x4_t qb = *(const f32x4_t*)(qp + 4);
            PK8(qa, qb, af[m][kk]);
        }
    __syncthreads();

    // ---- Phase 1: P^T-free swapped QK^T. D = mfma(A=K_frag, B=Q_frag):
    // lane(col,kg) reg r -> P[q=m*16+col][k = n0 + kg*4 + r] (4 consecutive k).
    float rs0 = 0.f, rs1 = 0.f;     // per-lane partial rowsum of q-row col / 16+col
    {
        const float* Kb = K + (size_t)b * S_LEN * HDIM;
        f32x4_t A0,B0,C0,D0, A1,B1,C1,D1, A2,B2,C2,D2, A3,B3,C3,D3;
#define LDK(f, AX,BX,CX,DX) { \
    const float* kp = Kb + (size_t)(w * 256 + (f) * 16 + col) * HDIM + kg * 8; \
    AX = *(const f32x4_t*)kp;        BX = *(const f32x4_t*)(kp + 4); \
    CX = *(const f32x4_t*)(kp + 32); DX = *(const f32x4_t*)(kp + 36); }
#define STEP(f, AX,BX,CX,DX, PF, fp) { \
    bf16x8_t kb0, kb1; PK8(AX, BX, kb0); PK8(CX, DX, kb1); \
    if (PF) LDK(fp, AX,BX,CX,DX); \
    f32x4_t acc0 = {0.f,0.f,0.f,0.f}, acc1 = {0.f,0.f,0.f,0.f}; \
    acc0 = __builtin_amdgcn_mfma_f32_16x16x32_bf16(kb0, af[0][0], acc0, 0,0,0); \
    acc0 = __builtin_amdgcn_mfma_f32_16x16x32_bf16(kb1, af[0][1], acc0, 0,0,0); \
    acc1 = __builtin_amdgcn_mfma_f32_16x16x32_bf16(kb0, af[1][0], acc1, 0,0,0); \
    acc1 = __builtin_amdgcn_mfma_f32_16x16x32_bf16(kb1, af[1][1], acc1, 0,0,0); \
    const int c0 = w * 256 + (f) * 16 + kg * 4; \
    const int sh = c0 & 7;            /* 0 or 4 */ \
    { const unsigned bb = Bm[col * BMSTR + (c0 >> 3)]; \
      float p0 = ((bb >> (sh    )) & 1u) ? 0.f : __expf(acc0[0] * 0.125f); \
      float p1 = ((bb >> (sh + 1)) & 1u) ? 0.f : __expf(acc0[1] * 0.125f); \
      float p2 = ((bb >> (sh + 2)) & 1u) ? 0.f : __expf(acc0[2] * 0.125f); \
      float p3 = ((bb >> (sh + 3)) & 1u) ? 0.f : __expf(acc0[3] * 0.125f); \
      rs0 += (p0 + p1) + (p2 + p3); \
      s16x4_t pk; pk[0]=f2bf(p0); pk[1]=f2bf(p1); pk[2]=f2bf(p2); pk[3]=f2bf(p3); \
      *(s16x4_t*)pelem(Plds, col, c0) = pk; } \
    { const unsigned bb = Bm[(16 + col) * BMSTR + (c0 >> 3)]; \
      float p0 = ((bb >> (sh    )) & 1u) ? 0.f : __expf(acc1[0] * 0.125f); \
      float p1 = ((bb >> (sh + 1)) & 1u) ? 0.f : __expf(acc1[1] * 0.125f); \
      float p2 = ((bb >> (sh + 2)) & 1u) ? 0.f : __expf(acc1[2] * 0.125f); \
      float p3 = ((bb >> (sh + 3)) & 1u) ? 0.f : __expf(acc1[3] * 0.125f); \
      rs1 += (p0 + p1) + (p2 + p3); \
      s16x4_t pk; pk[0]=f2bf(p0); pk[1]=f2bf(p1); pk[2]=f2bf(p2); pk[3]=f2bf(p3); \
      *(s16x4_t*)pelem(Plds, 16 + col, c0) = pk; } }
        LDK(0, A0,B0,C0,D0);
        LDK(1, A1,B1,C1,D1);
        LDK(2, A2,B2,C2,D2);
        LDK(3, A3,B3,C3,D3);
        #pragma unroll
        for (int ff = 0; ff < 16; ff += 4) {
            STEP(ff,     A0,B0,C0,D0, (ff + 4 < 16), ff + 4);
            STEP(ff + 1, A1,B1,C1,D1, (ff + 5 < 16), ff + 5);
            STEP(ff + 2, A2,B2,C2,D2, (ff + 6 < 16), ff + 6);
            STEP(ff + 3, A3,B3,C3,D3, (ff + 7 < 16), ff + 7);
        }
#undef LDK
#undef STEP
    }
    // rowsum: combine kg groups (lane, lane^16, lane^32, lane^48), one atomic
    {
        float s0 = rs0, s1 = rs1;
        s0 += __shfl_xor(s0, 16); s0 += __shfl_xor(s0, 32);
        s1 += __shfl_xor(s1, 16); s1 += __shfl_xor(s1, 32);
        if (lane < 16) {
            atomicAdd(&rowsum[col], s0);
            atomicAdd(&rowsum[16 + col], s1);
        }
    }
    __syncthreads();
    if (tid < BQ) rinv_s[tid] = 1.0f / rowsum[tid];
    __syncthreads();

    // ---- Phase 2a: pure PV, V prefetch depth 8
    const int hb    = (w & 3) * 16;
    const int kbase = (w >> 2) * 1024;
    const float* Vb = V + (size_t)b * S_LEN * HDIM;

    f32x4_t cacc0 = {0.f,0.f,0.f,0.f}, cacc1 = {0.f,0.f,0.f,0.f};
    {
        float vr0[8], vr1[8], vr2[8], vr3[8], vr4[8], vr5[8], vr6[8], vr7[8];
#define LOADV(kc, dst) { \
    const float* vp = Vb + (size_t)(kbase + (kc) * 32 + kg * 8) * HDIM + hb + col; \
    dst[0] = vp[0];        dst[1] = vp[HDIM];     dst[2] = vp[2*HDIM]; dst[3] = vp[3*HDIM]; \
    dst[4] = vp[4*HDIM];   dst[5] = vp[5*HDIM];   dst[6] = vp[6*HDIM]; dst[7] = vp[7*HDIM]; }
#define PVSTEP(kc, vsrc) { \
    bf16x8_t vbf; PKV(vsrc, vbf); \
    const int ke = kbase + (kc) * 32 + kg * 8; \
    const bf16x8_t pa0 = *(const bf16x8_t*)pelemc(Plds, col,      ke); \
    const bf16x8_t pa1 = *(const bf16x8_t*)pelemc(Plds, 16 + col, ke); \
    cacc0 = __builtin_amdgcn_mfma_f32_16x16x32_bf16(pa0, vbf, cacc0, 0,0,0); \
    cacc1 = __builtin_amdgcn_mfma_f32_16x16x32_bf16(pa1, vbf, cacc1, 0,0,0); }
        LOADV(0, vr0); LOADV(1, vr1); LOADV(2, vr2); LOADV(3, vr3);
        LOADV(4, vr4); LOADV(5, vr5); LOADV(6, vr6); LOADV(7, vr7);
        #pragma unroll
        for (int gg = 0; gg < 4; ++gg) {
            PVSTEP(8*gg,     vr0); if (8*gg +  8 < 32) LOADV(8*gg +  8, vr0);
            PVSTEP(8*gg + 1, vr1); if (8*gg +  9 < 32) LOADV(8*gg +  9, vr1);
            PVSTEP(8*gg + 2, vr2); if (8*gg + 10 < 32) LOADV(8*gg + 10, vr2);
            PVSTEP(8*gg + 3, vr3); if (8*gg + 11 < 32) LOADV(8*gg + 11, vr3);
            PVSTEP(8*gg + 4, vr4); if (8*gg + 12 < 32) LOADV(8*gg + 12, vr4);
            PVSTEP(8*gg + 5, vr5); if (8*gg + 13 < 32) LOADV(8*gg + 13, vr5);
            PVSTEP(8*gg + 6, vr6); if (8*gg + 14 < 32) LOADV(8*gg + 14, vr6);
            PVSTEP(8*gg + 7, vr7); if (8*gg + 15 < 32) LOADV(8*gg + 15, vr7);
        }
#undef LOADV
#undef PVSTEP
    }

    // ---- Phase 2b: attn store stream (proven ~free when overlapped)
    {
        const int srow = w * 4 + kg;
        const float my_rinv = rinv_s[srow];
        float* abp = attn_out + ((size_t)b * S_LEN + q0 + srow) * S_LEN + col * 4;
        #pragma unroll 4
        for (int sec = 0; sec < 32; ++sec) {
            const s16x4_t pv = *(const s16x4_t*)pelemc(Plds, srow, sec * 64 + col * 4);
            f32x4_t o;
            o[0] = bf2f(pv[0]) * my_rinv; o[1] = bf2f(pv[1]) * my_rinv;
            o[2] = bf2f(pv[2]) * my_rinv; o[3] = bf2f(pv[3]) * my_rinv;
            *(f32x4_t*)(abp + sec * 64) = o;
        }
    }

    // ---- ctx: reduce k-halves, normalize, store
    if (w >= 4) {
        #pragma unroll
        for (int r = 0; r < 4; ++r) {
            Pvp[w - 4][kg * 4 + r][col]      = cacc0[r];
            Pvp[w - 4][16 + kg * 4 + r][col] = cacc1[r];
        }
    }
    __syncthreads();
    if (w < 4) {
        #pragma unroll
        for (int r = 0; r < 4; ++r) {
            const int row0 = kg * 4 + r;
            const int row1 = 16 + kg * 4 + r;
            OUT[((size_t)b * S_LEN + q0 + row0) * HDIM + hb + col]
                = (cacc0[r] + Pvp[w][row0][col]) * rinv_s[row0];
            OUT[((size_t)b * S_LEN + q0 + row1) * HDIM + hb + col]
                = (cacc1[r] + Pvp[w][row1][col]) * rinv_s[row1];
        }
    }
}

extern "C" void kernel_launch(void* const* d_in, const int* in_sizes, int n_in,
                              void* d_out, int out_size, void* d_ws, size_t ws_size,
                              hipStream_t stream)
{
    const float* q = (const float*)d_in[0];
    const float* k = (const float*)d_in[1];
    const float* v = (const float*)d_in[2];
    const unsigned char* mask = (const unsigned char*)d_in[3];
    int* mflags = (int*)d_ws;
    float* out = (float*)d_out;
    detect_mask<<<dim3(1), dim3(256), 0, stream>>>(mask, mflags);
    sdpa_one<<<dim3(2048), dim3(NTHREADS), 0, stream>>>(q, k, v, mask, mflags, out);
}